// Round 3
// baseline (275.157 us; speedup 1.0000x reference)
//
#include <hip/hip_runtime.h>

// ---------------- problem constants ----------------
#define BATCH 2
#define NQ    4096        // em1 rows per batch
#define MK    4096        // em2 rows per batch
#define DD    256         // head dim
#define ODIM  512         // fc out
#define SDIM  512         // fc in (2*DD)

#define BM     32         // q rows per flash block
#define BK     128        // keys per inner tile (32 per wave)
#define MSPLIT 4
#define MCHUNK (MK / MSPLIT)   // 1024
#define NKT    (MCHUNK / BK)   // 8
#define XSPLIT (BATCH * NQ * DD)   // elements per X partial buffer
#define NROWS  (BATCH * NQ)        // 8192

typedef short bf16x8 __attribute__((ext_vector_type(8)));   // 8 bf16 in 4 VGPRs
typedef float f32x16 __attribute__((ext_vector_type(16)));

__device__ __forceinline__ float bf2f(unsigned short h) {
    unsigned int u = ((unsigned int)h) << 16;
    float f;
    __builtin_memcpy(&f, &u, 4);
    return f;
}
__device__ __forceinline__ unsigned short f2bf(float f) {
    unsigned int u;
    __builtin_memcpy(&u, &f, 4);
    u = (u + 0x7FFFu + ((u >> 16) & 1u)) >> 16;   // RNE
    return (unsigned short)u;
}
union frag_cast { uint4 u; bf16x8 b; unsigned short h[8]; };
__device__ __forceinline__ bf16x8 ldg_frag(const unsigned short* p) {
    frag_cast c;
    c.u = *(const uint4*)p;
    return c.b;
}

// ---------------- kernel 0: convert em1 (f32) and W (f32) to bf16 copies -----
__global__ void cvt_kernel(const float* em1, const float* W,
                           unsigned short* e1b, unsigned short* wb,
                           int n1, int ntot) {
    int e = (blockIdx.x * 256 + threadIdx.x) * 4;
    if (e >= ntot) return;
    const float* src;
    unsigned short* dst;
    if (e < n1) { src = em1 + e; dst = e1b + e; }
    else        { src = W + (e - n1); dst = wb + (e - n1); }
    float4 v = *(const float4*)src;
    ushort4 o;
    o.x = f2bf(v.x); o.y = f2bf(v.y); o.z = f2bf(v.z); o.w = f2bf(v.w);
    *(ushort4*)dst = o;
}

// ---------------- kernel 1: L2-normalize rows (one wave per row), f32 -> bf16 -
__global__ void norm_kernel(const float* em1, const float* em2,
                            unsigned short* qn, unsigned short* kn) {
    int row  = blockIdx.x * 4 + (threadIdx.x >> 6);   // 0..16383
    int lane = threadIdx.x & 63;
    const float* src;
    unsigned short* dst;
    if (row < BATCH * NQ) {
        src = em1 + (size_t)row * DD;
        dst = qn  + (size_t)row * DD;
    } else {
        int r = row - BATCH * NQ;
        src = em2 + (size_t)r * DD;
        dst = kn  + (size_t)r * DD;
    }
    float4 v = *(const float4*)(src + lane * 4);
    float ss = v.x * v.x + v.y * v.y + v.z * v.z + v.w * v.w;
#pragma unroll
    for (int off = 1; off < 64; off <<= 1) ss += __shfl_xor(ss, off, 64);
    float rn = rsqrtf(fmaxf(ss, 1e-6f));
    ushort4 o;
    o.x = f2bf(v.x * rn); o.y = f2bf(v.y * rn);
    o.z = f2bf(v.z * rn); o.w = f2bf(v.w * rn);
    *(ushort4*)(dst + lane * 4) = o;
}

// ---------------- kernel 2: transpose em2 (f32) -> vt bf16 [B][D][M] ----------
__global__ void transpose_kernel(const float* em2, unsigned short* vt) {
    __shared__ unsigned short T[64 * 68];
    int tid   = threadIdx.x;
    int bid   = blockIdx.x;
    int batch = bid >> 8;         // 256 tiles per batch
    int t2    = bid & 255;
    int mt = t2 >> 2, dt = t2 & 3;
    int m0 = mt * 64, d0 = dt * 64;
    const float* base = em2 + (size_t)batch * MK * DD;
#pragma unroll
    for (int it = 0; it < 4; it++) {
        int key = it * 16 + (tid >> 4);
        int dim = (tid & 15) * 4;
        float4 v = *(const float4*)(base + (size_t)(m0 + key) * DD + d0 + dim);
        ushort4 o;
        o.x = f2bf(v.x); o.y = f2bf(v.y); o.z = f2bf(v.z); o.w = f2bf(v.w);
        *(ushort4*)&T[key * 68 + dim] = o;
    }
    __syncthreads();
    unsigned short* obase = vt + (size_t)batch * DD * MK;
#pragma unroll
    for (int it = 0; it < 4; it++) {
        int dim  = it * 16 + (tid >> 4);
        int key4 = (tid & 15) * 4;
        ushort4 o;
        o.x = T[(key4 + 0) * 68 + dim];
        o.y = T[(key4 + 1) * 68 + dim];
        o.z = T[(key4 + 2) * 68 + dim];
        o.w = T[(key4 + 3) * 68 + dim];
        *(ushort4*)(obase + (size_t)(d0 + dim) * MK + m0 + key4) = o;
    }
}

// ---------------- kernel 3: flash attention (no-max softmax: s in [-1,1]) -----
// grid = 1024 blocks (256 rowblocks x 4 key-chunks), 256 threads (4 waves)
// block: 32 Q-rows x 128 keys per kt-iter. wave w: S-cols [32w,32w+32),
// X-dims [64w, 64w+64). Plain-store bf16 partials per split (no atomics).
__global__ __launch_bounds__(256, 3)
void flash_kernel(const unsigned short* qn, const unsigned short* kn,
                  const unsigned short* vt, unsigned short* Xp, float* lbuf) {
    __shared__ unsigned short P[BM * 136];   // 32 rows x 128 keys, +8 pad
    __shared__ float ls[4][BM];
    int tid   = threadIdx.x;
    int lane  = tid & 63;
    int w     = tid >> 6;
    int l31   = lane & 31;
    int lhalf = lane >> 5;
    int bid    = blockIdx.x;
    int mchunk = bid & 3;
    int rowblk = bid >> 2;            // 0..255
    int batch  = rowblk >> 7;         // 128 rowblocks per batch
    int r0     = rowblk * BM;         // global row in [0, 8192)

    const unsigned short* qbase =
        qn + (size_t)(r0 + l31) * DD + lhalf * 8;
    const unsigned short* kbase =
        kn + (size_t)(batch * MK + mchunk * MCHUNK + 32 * w + l31) * DD + lhalf * 8;
    const unsigned short* vbase =
        vt + (size_t)batch * DD * MK + (size_t)mchunk * MCHUNK + lhalf * 8;

    // preload Q A-frags (shared by all 4 waves: same 32 rows -> L1 broadcast)
    bf16x8 qf[16];
#pragma unroll
    for (int kk = 0; kk < 16; kk++) qf[kk] = ldg_frag(qbase + kk * 16);

    f32x16 xacc[2];
#pragma unroll
    for (int t = 0; t < 2; t++)
#pragma unroll
        for (int i = 0; i < 16; i++) xacc[t][i] = 0.f;
    float lpart[16];
#pragma unroll
    for (int i = 0; i < 16; i++) lpart[i] = 0.f;

    for (int kt = 0; kt < NKT; kt++) {
        // ---- QK^T: this wave's 32x32 S-tile, K over D=256 ----
        f32x16 sacc;
#pragma unroll
        for (int i = 0; i < 16; i++) sacc[i] = 0.f;
        const unsigned short* kp = kbase + (size_t)(kt * BK) * DD;
#pragma unroll
        for (int kk = 0; kk < 16; kk++) {
            bf16x8 bf = ldg_frag(kp + kk * 16);
            sacc = __builtin_amdgcn_mfma_f32_32x32x16_bf16(qf[kk], bf, sacc, 0, 0, 0);
        }
        __syncthreads();   // previous iteration's P reads complete
        // ---- P = exp(s-1) (cosine => max==1, no rescale), C-layout -> LDS ----
#pragma unroll
        for (int i = 0; i < 16; i++) {
            float p = __expf(sacc[i] - 1.0f);
            unsigned short pb = f2bf(p);
            lpart[i] += bf2f(pb);   // denominator from the SAME quantized weights
            int m = (i & 3) + 8 * (i >> 2) + 4 * lhalf;
            P[m * 136 + 32 * w + l31] = pb;
        }
        __syncthreads();
        // ---- PV: X[m][d] += P[m][key] * Vt[d][key], B-frags contiguous ----
        const unsigned short* vp = vbase + kt * BK;
#pragma unroll
        for (int ks = 0; ks < 8; ks++) {
            frag_cast ac;
            ac.u = *(const uint4*)&P[l31 * 136 + ks * 16 + lhalf * 8];
#pragma unroll
            for (int nt = 0; nt < 2; nt++) {
                int dcol = 64 * w + nt * 32 + l31;
                bf16x8 bf = ldg_frag(vp + (size_t)dcol * MK + ks * 16);
                xacc[nt] = __builtin_amdgcn_mfma_f32_32x32x16_bf16(ac.b, bf, xacc[nt], 0, 0, 0);
            }
        }
    }

    // ---- l: reduce over this wave's 32 key-cols, combine waves via LDS ----
#pragma unroll
    for (int i = 0; i < 16; i++) {
        float v = lpart[i];
#pragma unroll
        for (int off = 1; off < 32; off <<= 1) v += __shfl_xor(v, off, 64);
        if (l31 == 0) {
            int m = (i & 3) + 8 * (i >> 2) + 4 * lhalf;
            ls[w][m] = v;
        }
    }
    __syncthreads();
    if (tid < BM) {
        float s = ls[0][tid] + ls[1][tid] + ls[2][tid] + ls[3][tid];
        lbuf[(size_t)mchunk * NROWS + r0 + tid] = s;
    }
    // ---- store X partial (bf16, disjoint dims per wave, no atomics) ----
    unsigned short* xout = Xp + (size_t)mchunk * XSPLIT;
#pragma unroll
    for (int nt = 0; nt < 2; nt++) {
        int dcol = 64 * w + nt * 32 + l31;
#pragma unroll
        for (int i = 0; i < 16; i++) {
            int m = (i & 3) + 8 * (i >> 2) + 4 * lhalf;
            xout[(size_t)(r0 + m) * DD + dcol] = f2bf(xacc[nt][i]);
        }
    }
}

// ---------------- kernel 4: h = relu([em1, (ΣX)/(Σl)] @ W^T + b), f32 out -----
// grid = 256 blocks (64 row-blocks x 4 col-blocks), 256 threads (4 waves)
__global__ __launch_bounds__(256, 2)
void final_gemm(const unsigned short* e1b, const unsigned short* Xp,
                const float* lbuf, const unsigned short* wb, const float* bias,
                float* out) {
    int tid   = threadIdx.x;
    int lane  = tid & 63;
    int w     = tid >> 6;
    int l31   = lane & 31;
    int lhalf = lane >> 5;
    int bid = blockIdx.x;
    int cb = bid & 3;
    int rb = bid >> 2;
    int R0 = rb * 128 + 64 * (w & 1);
    int C0 = cb * 128 + 64 * (w >> 1);

    f32x16 acc[2][2];
#pragma unroll
    for (int a = 0; a < 2; a++)
#pragma unroll
        for (int b2 = 0; b2 < 2; b2++)
#pragma unroll
            for (int i = 0; i < 16; i++) acc[a][b2][i] = 0.f;

    int   rA[2];
    float rinv[2];
#pragma unroll
    for (int mt = 0; mt < 2; mt++) {
        rA[mt] = R0 + mt * 32 + l31;
        float l = lbuf[rA[mt]] + lbuf[NROWS + rA[mt]] +
                  lbuf[2 * NROWS + rA[mt]] + lbuf[3 * NROWS + rA[mt]];
        rinv[mt] = 1.0f / l;
    }

    for (int kk = 0; kk < 32; kk++) {   // K = 512, steps of 16
        int k0 = kk * 16 + lhalf * 8;
        bf16x8 afr[2];
        if (kk < 16) {
            // emb[:, 0:256] = em1 (pre-converted bf16)
#pragma unroll
            for (int mt = 0; mt < 2; mt++)
                afr[mt] = ldg_frag(e1b + (size_t)rA[mt] * DD + k0);
        } else {
            // emb[:, 256:512] = (sum of split partials) / l -> bf16
#pragma unroll
            for (int mt = 0; mt < 2; mt++) {
                const unsigned short* xb = Xp + (size_t)rA[mt] * DD + (k0 - 256);
                frag_cast p0, p1, p2, p3, u;
                p0.u = *(const uint4*)xb;
                p1.u = *(const uint4*)(xb + XSPLIT);
                p2.u = *(const uint4*)(xb + 2 * (size_t)XSPLIT);
                p3.u = *(const uint4*)(xb + 3 * (size_t)XSPLIT);
#pragma unroll
                for (int j = 0; j < 8; j++) {
                    float f = bf2f(p0.h[j]) + bf2f(p1.h[j]) +
                              bf2f(p2.h[j]) + bf2f(p3.h[j]);
                    u.h[j] = f2bf(f * rinv[mt]);
                }
                afr[mt] = u.b;
            }
        }
        bf16x8 bfr[2];
#pragma unroll
        for (int nt = 0; nt < 2; nt++)
            bfr[nt] = ldg_frag(wb + (size_t)(C0 + nt * 32 + l31) * SDIM + k0);
#pragma unroll
        for (int mt = 0; mt < 2; mt++)
#pragma unroll
            for (int nt = 0; nt < 2; nt++)
                acc[mt][nt] = __builtin_amdgcn_mfma_f32_32x32x16_bf16(
                    afr[mt], bfr[nt], acc[mt][nt], 0, 0, 0);
    }

#pragma unroll
    for (int nt = 0; nt < 2; nt++) {
        int col = C0 + nt * 32 + l31;
        float bb = bias[col];
#pragma unroll
        for (int mt = 0; mt < 2; mt++) {
#pragma unroll
            for (int i = 0; i < 16; i++) {
                int row = R0 + mt * 32 + (i & 3) + 8 * (i >> 2) + 4 * lhalf;
                float v = acc[mt][nt][i] + bb;
                v = v > 0.f ? v : 0.f;
                out[(size_t)row * ODIM + col] = v;
            }
        }
    }
}

// ---------------- launch ----------------
extern "C" void kernel_launch(void* const* d_in, const int* in_sizes, int n_in,
                              void* d_out, int out_size, void* d_ws, size_t ws_size,
                              hipStream_t stream) {
    const float* em1  = (const float*)d_in[0];
    const float* em2  = (const float*)d_in[1];
    const float* W    = (const float*)d_in[2];
    const float* bias = (const float*)d_in[3];
    float* out = (float*)d_out;

    char* ws = (char*)d_ws;
    unsigned short* qn  = (unsigned short*)ws;                      // 4 MB
    unsigned short* kn  = qn + (size_t)BATCH * NQ * DD;             // 4 MB
    unsigned short* vt  = kn + (size_t)BATCH * MK * DD;             // 4 MB
    unsigned short* e1b = vt + (size_t)BATCH * DD * MK;             // 4 MB
    unsigned short* wb  = e1b + (size_t)BATCH * NQ * DD;            // 0.5 MB
    unsigned short* Xp  = (unsigned short*)(ws + 17ull * 1024 * 1024);  // 16 MB (4 splits bf16)
    float* lbuf = (float*)(ws + 33ull * 1024 * 1024);               // 128 KB (4 splits)

    const int n1   = BATCH * NQ * DD;           // em1 elements
    const int ntot = n1 + ODIM * SDIM;          // + W elements
    cvt_kernel<<<(ntot / 4 + 255) / 256, 256, 0, stream>>>(em1, W, e1b, wb, n1, ntot);
    norm_kernel<<<(BATCH * (NQ + MK)) / 4, 256, 0, stream>>>(em1, em2, qn, kn);
    transpose_kernel<<<BATCH * (MK / 64) * (DD / 64), 256, 0, stream>>>(em2, vt);
    flash_kernel<<<(BATCH * NQ / BM) * MSPLIT, 256, 0, stream>>>(qn, kn, vt, Xp, lbuf);
    final_gemm<<<(BATCH * NQ / 128) * (ODIM / 128), 256, 0, stream>>>(
        e1b, Xp, lbuf, wb, bias, out);
}

// Round 4
// 255.911 us; speedup vs baseline: 1.0752x; 1.0752x over previous
//
#include <hip/hip_runtime.h>

// ---------------- problem constants ----------------
#define BATCH 2
#define NQ    4096
#define MK    4096
#define DD    256
#define ODIM  512
#define SDIM  512
#define NROWS (BATCH * NQ)          // 8192
#define BM    32                    // q rows per flash block
#define BK    128                   // keys per kt iter (32 per wave)
#define MSPLIT 4
#define MCHUNK (MK / MSPLIT)        // 1024
#define NKT    (MCHUNK / BK)        // 8
#define XSPLIT (BATCH * NQ * DD)    // 2097152 elements per X partial split

// chunk counts (1 chunk = 8 shorts = 16B)
#define NCH_E1 (NROWS * DD / 8)     // 262144
#define NCH_K  NCH_E1
#define NCH_V  NCH_E1
#define NCH_W  (ODIM * SDIM / 8)    // 32768

typedef short bf16x8 __attribute__((ext_vector_type(8)));
typedef float f32x16 __attribute__((ext_vector_type(16)));

__device__ __forceinline__ float bf2f(unsigned short h) {
    unsigned int u = ((unsigned int)h) << 16;
    float f;
    __builtin_memcpy(&f, &u, 4);
    return f;
}
__device__ __forceinline__ unsigned short f2bf(float f) {
    unsigned int u;
    __builtin_memcpy(&u, &f, 4);
    u = (u + 0x7FFFu + ((u >> 16) & 1u)) >> 16;   // RNE
    return (unsigned short)u;
}
union frag_cast { uint4 u; bf16x8 b; unsigned short h[8]; };
__device__ __forceinline__ bf16x8 ldg_frag(const unsigned short* p) {
    frag_cast c;
    c.u = *(const uint4*)p;
    return c.b;
}

// ---------------- kernel 1: per-row rsqrt(max(||x||^2, eps)) ----------------
// rn[0..8191] = em1 rows, rn[8192..16383] = em2 rows. One wave per row.
__global__ void rnorm_kernel(const float* em1, const float* em2, float* rn) {
    int row  = blockIdx.x * 4 + (threadIdx.x >> 6);
    int lane = threadIdx.x & 63;
    const float* src = (row < NROWS) ? em1 + (size_t)row * DD
                                     : em2 + (size_t)(row - NROWS) * DD;
    float4 v = *(const float4*)(src + lane * 4);
    float ss = v.x * v.x + v.y * v.y + v.z * v.z + v.w * v.w;
#pragma unroll
    for (int off = 1; off < 64; off <<= 1) ss += __shfl_xor(ss, off, 64);
    if (lane == 0) rn[row] = rsqrtf(fmaxf(ss, 1e-6f));
}

// ---------------- kernel 2: swizzle all operands into MFMA-fragment order ----
// row-swizzle (e1sw/ksw/wsw): group g = 32 rows; chunk c = kk*64+lh*32+r31
//   holds element(row=g*32+r31, k = (c>>5)*8 + j), stored at (g*chunks+c)*8+j.
// dim-swizzle (vsw): chunk holds (dim = dg*32+d31, keys oct*8+j) at
//   b*1048576 + dg*131072 + oct*256 + d31*8 + j.
__global__ void swizzle_kernel(const float* em1, const float* em2, const float* W,
                               unsigned short* e1sw, unsigned short* ksw,
                               unsigned short* vsw, unsigned short* wsw) {
    int cg = blockIdx.x * 256 + threadIdx.x;
    if (cg < NCH_E1 + NCH_K) {
        const float* src;
        unsigned short* dst;
        int c0;
        if (cg < NCH_E1) { src = em1; dst = e1sw; c0 = cg; }
        else             { src = em2; dst = ksw;  c0 = cg - NCH_E1; }
        int g = c0 >> 10, c = c0 & 1023;
        int r31 = c & 31;
        int k0  = (c >> 5) * 8;
        const float* sp = src + (size_t)(g * 32 + r31) * DD + k0;
        float4 a = *(const float4*)sp;
        float4 b = *(const float4*)(sp + 4);
        ushort4 o1, o2;
        o1.x = f2bf(a.x); o1.y = f2bf(a.y); o1.z = f2bf(a.z); o1.w = f2bf(a.w);
        o2.x = f2bf(b.x); o2.y = f2bf(b.y); o2.z = f2bf(b.z); o2.w = f2bf(b.w);
        *(ushort4*)(dst + (size_t)c0 * 8)     = o1;
        *(ushort4*)(dst + (size_t)c0 * 8 + 4) = o2;
    } else if (cg < NCH_E1 + NCH_K + NCH_V) {
        int c0 = cg - (NCH_E1 + NCH_K);
        int b   = c0 >> 17;          // 131072 chunks per batch
        int r   = c0 & 131071;
        int dg  = r >> 14;           // dim-group (32 dims)
        int rr  = r & 16383;
        int oct = rr >> 5;           // key octet
        int d31 = rr & 31;
        const float* sp = em2 + (size_t)(b * MK + oct * 8) * DD + dg * 32 + d31;
        ushort4 o1, o2;
        o1.x = f2bf(sp[0 * DD]); o1.y = f2bf(sp[1 * DD]);
        o1.z = f2bf(sp[2 * DD]); o1.w = f2bf(sp[3 * DD]);
        o2.x = f2bf(sp[4 * DD]); o2.y = f2bf(sp[5 * DD]);
        o2.z = f2bf(sp[6 * DD]); o2.w = f2bf(sp[7 * DD]);
        *(ushort4*)(vsw + (size_t)c0 * 8)     = o1;
        *(ushort4*)(vsw + (size_t)c0 * 8 + 4) = o2;
    } else {
        int c0 = cg - (NCH_E1 + NCH_K + NCH_V);
        if (c0 >= NCH_W) return;
        int g = c0 >> 11, c = c0 & 2047;       // 2048 chunks per 32-col group
        int c31 = c & 31;
        int k0  = (c >> 5) * 8;
        const float* sp = W + (size_t)(g * 32 + c31) * SDIM + k0;
        float4 a = *(const float4*)sp;
        float4 b = *(const float4*)(sp + 4);
        ushort4 o1, o2;
        o1.x = f2bf(a.x); o1.y = f2bf(a.y); o1.z = f2bf(a.z); o1.w = f2bf(a.w);
        o2.x = f2bf(b.x); o2.y = f2bf(b.y); o2.z = f2bf(b.z); o2.w = f2bf(b.w);
        *(ushort4*)(wsw + (size_t)c0 * 8)     = o1;
        *(ushort4*)(wsw + (size_t)c0 * 8 + 4) = o2;
    }
}

// ---------------- kernel 3: flash attention, raw QK + post-scale by rq*rk ----
// grid = 1024 (mchunk = bid>>8 for per-XCD L2 chunk sharing), 4 waves/block.
// All frag loads are lane-contiguous 1KB streams from swizzled buffers.
__global__ __launch_bounds__(256, 3)
void flash_kernel(const unsigned short* e1sw, const unsigned short* ksw,
                  const unsigned short* vsw, const float* rn,
                  unsigned short* Xp, float* lbuf) {
    __shared__ unsigned short P[BM * 136];
    __shared__ float ls[4][BM];
    int tid = threadIdx.x, lane = tid & 63, w = tid >> 6;
    int l31 = lane & 31, lhalf = lane >> 5;
    int bid    = blockIdx.x;
    int mchunk = bid >> 8;
    int rowblk = bid & 255;
    int batch  = rowblk >> 7;
    int r0     = rowblk * BM;

    // Q A-frags (raw em1, swizzled; shared by all 4 waves -> L1 broadcast)
    const unsigned short* qbase = e1sw + (size_t)rowblk * 8192 + lhalf * 256 + l31 * 8;
    bf16x8 qf[16];
#pragma unroll
    for (int kk = 0; kk < 16; kk++) qf[kk] = ldg_frag(qbase + kk * 512);

    // per-C-reg query rsqrt-norms
    float rqv[16];
#pragma unroll
    for (int i = 0; i < 16; i++) {
        int m = (i & 3) + 8 * (i >> 2) + 4 * lhalf;
        rqv[i] = rn[r0 + m];
    }
    const float* rnk = rn + NROWS + batch * MK + mchunk * MCHUNK;

    f32x16 xacc[2];
#pragma unroll
    for (int t = 0; t < 2; t++)
#pragma unroll
        for (int i = 0; i < 16; i++) xacc[t][i] = 0.f;
    float lpart[16];
#pragma unroll
    for (int i = 0; i < 16; i++) lpart[i] = 0.f;

    for (int kt = 0; kt < NKT; kt++) {
        // ---- QK^T (raw): wave w handles keys [kt*128 + 32w, +32) ----
        f32x16 sacc;
#pragma unroll
        for (int i = 0; i < 16; i++) sacc[i] = 0.f;
        int kgrp = batch * 128 + mchunk * 32 + kt * 4 + w;
        const unsigned short* kp = ksw + (size_t)kgrp * 8192 + lhalf * 256 + l31 * 8;
#pragma unroll
        for (int kk = 0; kk < 16; kk++) {
            bf16x8 bf = ldg_frag(kp + kk * 512);
            sacc = __builtin_amdgcn_mfma_f32_32x32x16_bf16(qf[kk], bf, sacc, 0, 0, 0);
        }
        float rk = rnk[kt * BK + w * 32 + l31];
        __syncthreads();   // previous iteration's P reads complete
        // ---- P = exp(s*rq*rk - 1)  (cosine => max = 1, no rescale) ----
#pragma unroll
        for (int i = 0; i < 16; i++) {
            float p = __expf(sacc[i] * rqv[i] * rk - 1.0f);
            unsigned short pb = f2bf(p);
            lpart[i] += bf2f(pb);   // denominator from the SAME quantized weights
            int m = (i & 3) + 8 * (i >> 2) + 4 * lhalf;
            P[m * 136 + 32 * w + l31] = pb;
        }
        __syncthreads();
        // ---- PV: B-frags stream contiguously from vsw ----
        const unsigned short* vp = vsw + (size_t)batch * 1048576 +
                                   (size_t)(mchunk * 128 + kt * 16) * 256 +
                                   lhalf * 256 + l31 * 8;
#pragma unroll
        for (int ks = 0; ks < 8; ks++) {
            frag_cast ac;
            ac.u = *(const uint4*)&P[l31 * 136 + ks * 16 + lhalf * 8];
#pragma unroll
            for (int nt = 0; nt < 2; nt++) {
                int dg = 2 * w + nt;
                bf16x8 bf = ldg_frag(vp + (size_t)dg * 131072 + ks * 512);
                xacc[nt] = __builtin_amdgcn_mfma_f32_32x32x16_bf16(ac.b, bf, xacc[nt], 0, 0, 0);
            }
        }
    }

    // ---- l: reduce over this wave's 32 key-cols, combine waves via LDS ----
#pragma unroll
    for (int i = 0; i < 16; i++) {
        float v = lpart[i];
#pragma unroll
        for (int off = 1; off < 32; off <<= 1) v += __shfl_xor(v, off, 64);
        if (l31 == 0) {
            int m = (i & 3) + 8 * (i >> 2) + 4 * lhalf;
            ls[w][m] = v;
        }
    }
    __syncthreads();
    if (tid < BM) {
        float s = ls[0][tid] + ls[1][tid] + ls[2][tid] + ls[3][tid];
        lbuf[(size_t)mchunk * NROWS + r0 + tid] = s;
    }
    // ---- store X partial in row-swizzled layout (bf16, no atomics) ----
    unsigned short* xout = Xp + (size_t)mchunk * XSPLIT + (size_t)rowblk * 8192;
#pragma unroll
    for (int nt = 0; nt < 2; nt++) {
        int dcol = 64 * w + nt * 32 + l31;
        int cbase = (dcol >> 3) * 256 + (dcol & 7);
#pragma unroll
        for (int i = 0; i < 16; i++) {
            int m = (i & 3) + 8 * (i >> 2) + 4 * lhalf;
            xout[cbase + m * 8] = f2bf(xacc[nt][i]);
        }
    }
}

// ---------------- kernel 4: xnsw = (sum of 4 X splits) / (sum l), swizzled ----
__global__ void reduce_kernel(const unsigned short* Xp, const float* lbuf,
                              unsigned short* xnsw) {
    int cg  = blockIdx.x * 256 + threadIdx.x;   // 262144 chunks
    int row = (cg >> 10) * 32 + (cg & 31);
    float l = lbuf[row] + lbuf[NROWS + row] +
              lbuf[2 * NROWS + row] + lbuf[3 * NROWS + row];
    float rinv = 1.0f / l;
    const unsigned short* p = Xp + (size_t)cg * 8;
    frag_cast p0, p1, p2, p3, u;
    p0.u = *(const uint4*)p;
    p1.u = *(const uint4*)(p + (size_t)XSPLIT);
    p2.u = *(const uint4*)(p + 2 * (size_t)XSPLIT);
    p3.u = *(const uint4*)(p + 3 * (size_t)XSPLIT);
#pragma unroll
    for (int j = 0; j < 8; j++) {
        float f = bf2f(p0.h[j]) + bf2f(p1.h[j]) + bf2f(p2.h[j]) + bf2f(p3.h[j]);
        u.h[j] = f2bf(f * rinv);
    }
    *(uint4*)(xnsw + (size_t)cg * 8) = u.u;
}

// ---------------- kernel 5: h = relu([em1, xn] @ W^T + b), all swizzled ------
__global__ __launch_bounds__(256, 2)
void final_gemm(const unsigned short* e1sw, const unsigned short* xnsw,
                const unsigned short* wsw, const float* bias, float* out) {
    int tid = threadIdx.x, lane = tid & 63, w = tid >> 6;
    int l31 = lane & 31, lhalf = lane >> 5;
    int bid = blockIdx.x;
    int cb = bid & 3, rb = bid >> 2;
    int R0 = rb * 128 + 64 * (w & 1);
    int C0 = cb * 128 + 64 * (w >> 1);

    f32x16 acc[2][2];
#pragma unroll
    for (int a = 0; a < 2; a++)
#pragma unroll
        for (int b2 = 0; b2 < 2; b2++)
#pragma unroll
            for (int i = 0; i < 16; i++) acc[a][b2][i] = 0.f;

    for (int kk = 0; kk < 32; kk++) {   // K = 512 in steps of 16
        bf16x8 afr[2], bfr[2];
#pragma unroll
        for (int mt = 0; mt < 2; mt++) {
            int gA = (R0 >> 5) + mt;
            const unsigned short* ap =
                (kk < 16) ? e1sw + (size_t)gA * 8192 + kk * 512
                          : xnsw + (size_t)gA * 8192 + (kk - 16) * 512;
            afr[mt] = ldg_frag(ap + lhalf * 256 + l31 * 8);
        }
#pragma unroll
        for (int nt = 0; nt < 2; nt++) {
            int gB = (C0 >> 5) + nt;
            bfr[nt] = ldg_frag(wsw + (size_t)gB * 16384 + kk * 512 + lhalf * 256 + l31 * 8);
        }
#pragma unroll
        for (int mt = 0; mt < 2; mt++)
#pragma unroll
            for (int nt = 0; nt < 2; nt++)
                acc[mt][nt] = __builtin_amdgcn_mfma_f32_32x32x16_bf16(
                    afr[mt], bfr[nt], acc[mt][nt], 0, 0, 0);
    }

#pragma unroll
    for (int nt = 0; nt < 2; nt++) {
        int col = C0 + nt * 32 + l31;
        float bb = bias[col];
#pragma unroll
        for (int mt = 0; mt < 2; mt++) {
#pragma unroll
            for (int i = 0; i < 16; i++) {
                int row = R0 + mt * 32 + (i & 3) + 8 * (i >> 2) + 4 * lhalf;
                float v = acc[mt][nt][i] + bb;
                v = v > 0.f ? v : 0.f;
                out[(size_t)row * ODIM + col] = v;
            }
        }
    }
}

// ---------------- launch ----------------
extern "C" void kernel_launch(void* const* d_in, const int* in_sizes, int n_in,
                              void* d_out, int out_size, void* d_ws, size_t ws_size,
                              hipStream_t stream) {
    const float* em1  = (const float*)d_in[0];
    const float* em2  = (const float*)d_in[1];
    const float* W    = (const float*)d_in[2];
    const float* bias = (const float*)d_in[3];
    float* out = (float*)d_out;

    char* ws = (char*)d_ws;
    unsigned short* e1sw = (unsigned short*)ws;                     // 4 MB
    unsigned short* ksw  = e1sw + (size_t)NROWS * DD;               // 4 MB
    unsigned short* vsw  = ksw  + (size_t)NROWS * DD;               // 4 MB
    unsigned short* wsw  = vsw  + (size_t)BATCH * DD * MK;          // 0.5 MB
    unsigned short* Xp   = wsw  + (size_t)ODIM * SDIM;              // 16 MB
    unsigned short* xnsw = Xp   + 4 * (size_t)XSPLIT;               // 4 MB
    float* lbuf = (float*)(xnsw + (size_t)NROWS * DD);              // 128 KB
    float* rn   = lbuf + 4 * (size_t)NROWS;                        // 64 KB

    rnorm_kernel<<<(2 * NROWS) / 4, 256, 0, stream>>>(em1, em2, rn);
    swizzle_kernel<<<(NCH_E1 + NCH_K + NCH_V + NCH_W + 255) / 256, 256, 0, stream>>>(
        em1, em2, W, e1sw, ksw, vsw, wsw);
    flash_kernel<<<MSPLIT * 256, 256, 0, stream>>>(e1sw, ksw, vsw, rn, Xp, lbuf);
    reduce_kernel<<<NCH_E1 / 256, 256, 0, stream>>>(Xp, lbuf, xnsw);
    final_gemm<<<(NROWS / 128) * (ODIM / 128), 256, 0, stream>>>(
        e1sw, xnsw, wsw, bias, out);
}

// Round 5
// 155.647 us; speedup vs baseline: 1.7678x; 1.6442x over previous
//
#include <hip/hip_runtime.h>

// ---------------- problem constants ----------------
#define BATCH 2
#define NQ    4096
#define MK    4096
#define DD    256
#define ODIM  512
#define SDIM  512
#define NROWS (BATCH * NQ)          // 8192
#define BM    64                    // q rows per flash block
#define BK    64                    // keys per kt iter
#define MSPLIT 4
#define MCHUNK (MK / MSPLIT)        // 1024
#define NKT    (MCHUNK / BK)        // 16
#define XSPLIT (BATCH * NQ * DD)    // elements per X partial split

// chunk counts (1 chunk = 8 shorts = 16B)
#define NCH_E1 (NROWS * DD / 8)     // 262144
#define NCH_K  NCH_E1
#define NCH_V  NCH_E1
#define NCH_W  (ODIM * SDIM / 8)    // 32768

typedef short bf16x8 __attribute__((ext_vector_type(8)));
typedef float f32x16 __attribute__((ext_vector_type(16)));

__device__ __forceinline__ float bf2f(unsigned short h) {
    unsigned int u = ((unsigned int)h) << 16;
    float f;
    __builtin_memcpy(&f, &u, 4);
    return f;
}
__device__ __forceinline__ unsigned short f2bf(float f) {
    unsigned int u;
    __builtin_memcpy(&u, &f, 4);
    u = (u + 0x7FFFu + ((u >> 16) & 1u)) >> 16;   // RNE
    return (unsigned short)u;
}
union frag_cast { uint4 u; bf16x8 b; unsigned short h[8]; };
__device__ __forceinline__ bf16x8 ldg_frag(const unsigned short* p) {
    frag_cast c;
    c.u = *(const uint4*)p;
    return c.b;
}
// async global -> LDS, 16B per lane (global_load_lds_dwordx4)
__device__ __forceinline__ void load_lds16(const unsigned short* g, unsigned short* l) {
    __builtin_amdgcn_global_load_lds(
        (const __attribute__((address_space(1))) void*)g,
        (__attribute__((address_space(3))) void*)l, 16, 0, 0);
}

// ---------------- kernel 1: per-row rsqrt(max(||x||^2, eps)) ----------------
__global__ void rnorm_kernel(const float* em1, const float* em2, float* rn) {
    int row  = blockIdx.x * 4 + (threadIdx.x >> 6);
    int lane = threadIdx.x & 63;
    const float* src = (row < NROWS) ? em1 + (size_t)row * DD
                                     : em2 + (size_t)(row - NROWS) * DD;
    float4 v = *(const float4*)(src + lane * 4);
    float ss = v.x * v.x + v.y * v.y + v.z * v.z + v.w * v.w;
#pragma unroll
    for (int off = 1; off < 64; off <<= 1) ss += __shfl_xor(ss, off, 64);
    if (lane == 0) rn[row] = rsqrtf(fmaxf(ss, 1e-6f));
}

// ---------------- kernel 2: swizzle operands into MFMA-fragment order --------
// row-frag order (e1sw/ksw/wsw): group g = 32 rows; element (r,k) at
//   g*32*K + (k>>3)*256 + (r&31)*8 + (k&7)
// dim-frag order (vsw): per batch, dim-group dg = 32 dims over K=4096 keys.
__global__ void swizzle_kernel(const float* em1, const float* em2, const float* W,
                               unsigned short* e1sw, unsigned short* ksw,
                               unsigned short* vsw, unsigned short* wsw) {
    int cg = blockIdx.x * 256 + threadIdx.x;
    if (cg < NCH_E1 + NCH_K) {
        const float* src;
        unsigned short* dst;
        int c0;
        if (cg < NCH_E1) { src = em1; dst = e1sw; c0 = cg; }
        else             { src = em2; dst = ksw;  c0 = cg - NCH_E1; }
        int g = c0 >> 10, c = c0 & 1023;
        int r31 = c & 31;
        int k0  = (c >> 5) * 8;
        const float* sp = src + (size_t)(g * 32 + r31) * DD + k0;
        float4 a = *(const float4*)sp;
        float4 b = *(const float4*)(sp + 4);
        ushort4 o1, o2;
        o1.x = f2bf(a.x); o1.y = f2bf(a.y); o1.z = f2bf(a.z); o1.w = f2bf(a.w);
        o2.x = f2bf(b.x); o2.y = f2bf(b.y); o2.z = f2bf(b.z); o2.w = f2bf(b.w);
        *(ushort4*)(dst + (size_t)c0 * 8)     = o1;
        *(ushort4*)(dst + (size_t)c0 * 8 + 4) = o2;
    } else if (cg < NCH_E1 + NCH_K + NCH_V) {
        int c0 = cg - (NCH_E1 + NCH_K);
        int b   = c0 >> 17;
        int r   = c0 & 131071;
        int dg  = r >> 14;
        int rr  = r & 16383;
        int oct = rr >> 5;
        int d31 = rr & 31;
        const float* sp = em2 + (size_t)(b * MK + oct * 8) * DD + dg * 32 + d31;
        ushort4 o1, o2;
        o1.x = f2bf(sp[0 * DD]); o1.y = f2bf(sp[1 * DD]);
        o1.z = f2bf(sp[2 * DD]); o1.w = f2bf(sp[3 * DD]);
        o2.x = f2bf(sp[4 * DD]); o2.y = f2bf(sp[5 * DD]);
        o2.z = f2bf(sp[6 * DD]); o2.w = f2bf(sp[7 * DD]);
        *(ushort4*)(vsw + (size_t)c0 * 8)     = o1;
        *(ushort4*)(vsw + (size_t)c0 * 8 + 4) = o2;
    } else {
        int c0 = cg - (NCH_E1 + NCH_K + NCH_V);
        if (c0 >= NCH_W) return;
        int g = c0 >> 11, c = c0 & 2047;
        int c31 = c & 31;
        int k0  = (c >> 5) * 8;
        const float* sp = W + (size_t)(g * 32 + c31) * SDIM + k0;
        float4 a = *(const float4*)sp;
        float4 b = *(const float4*)(sp + 4);
        ushort4 o1, o2;
        o1.x = f2bf(a.x); o1.y = f2bf(a.y); o1.z = f2bf(a.z); o1.w = f2bf(a.w);
        o2.x = f2bf(b.x); o2.y = f2bf(b.y); o2.z = f2bf(b.z); o2.w = f2bf(b.w);
        *(ushort4*)(wsw + (size_t)c0 * 8)     = o1;
        *(ushort4*)(wsw + (size_t)c0 * 8 + 4) = o2;
    }
}

// ---------------- kernel 3: flash attention, m97-style LDS staging -----------
// grid = 512 (mchunk = bid>>7), 256 threads = 4 waves.
// Block: 64 Q-rows x 1024 keys in BK=64 steps. Wave (wr=w&1, wc=w>>1):
//   QK: S rows wr*32+[0,32), keys wc*32+[0,32). PV: rows wr*32, dims wc*128.
// K/V tiles staged to LDS via async global_load_lds (16B/lane); frags ds_read.
__global__ __launch_bounds__(256, 2)
void flash_kernel(const unsigned short* e1sw, const unsigned short* ksw,
                  const unsigned short* vsw, const float* rn,
                  unsigned short* Xp, float* lbuf) {
    __shared__ unsigned short Ks[16384];   // 64 keys x 256 dims, frag order
    __shared__ unsigned short Vs[16384];   // 256 dims x 64 keys, frag order
    __shared__ unsigned short Ps[BM * 72]; // 64 rows x 64 keys, row stride 72
    __shared__ float ls[2][BM];
    int tid = threadIdx.x, lane = tid & 63, w = tid >> 6;
    int l31 = lane & 31, lhalf = lane >> 5;
    int wr = w & 1, wc = w >> 1;
    int bid    = blockIdx.x;
    int mchunk = bid >> 7;
    int rowblk = bid & 127;
    int batch  = rowblk >> 6;
    int r0     = rowblk * BM;

    // Q A-frags, register-resident for the whole block sweep
    const unsigned short* qbase =
        e1sw + (size_t)(rowblk * 2 + wr) * 8192 + lhalf * 256 + l31 * 8;
    bf16x8 qf[16];
#pragma unroll
    for (int s = 0; s < 16; s++) qf[s] = ldg_frag(qbase + s * 512);

    float rqv[16];
#pragma unroll
    for (int i = 0; i < 16; i++) {
        int m = (i & 3) + 8 * (i >> 2) + 4 * lhalf;
        rqv[i] = rn[r0 + wr * 32 + m];
    }
    const float* rnk = rn + NROWS + batch * MK + mchunk * MCHUNK;

    const unsigned short* kchunk = ksw + (size_t)(batch * 128 + mchunk * 32) * 8192;
    const unsigned short* vbase  = vsw + (size_t)batch * 1048576 +
                                   (size_t)(mchunk * 128) * 256;

    f32x16 xacc[4];
#pragma unroll
    for (int t = 0; t < 4; t++)
#pragma unroll
        for (int i = 0; i < 16; i++) xacc[t][i] = 0.f;
    float lpart[16];
#pragma unroll
    for (int i = 0; i < 16; i++) lpart[i] = 0.f;

    for (int kt = 0; kt < NKT; kt++) {
        __syncthreads();   // prior PV reads of Ks/Vs complete
        // ---- stage K-tile (32 KB contiguous) + V-tile (8 x 4 KB) ----
        {
            const unsigned short* ksrc = kchunk + (size_t)kt * 16384;
#pragma unroll
            for (int it = 0; it < 8; it++)
                load_lds16(ksrc + it * 2048 + tid * 8, &Ks[it * 2048 + tid * 8]);
            const unsigned short* vsrc = vbase + (size_t)(kt * 8) * 256;
#pragma unroll
            for (int dg = 0; dg < 8; dg++)
                load_lds16(vsrc + (size_t)dg * 131072 + tid * 8, &Vs[dg * 2048 + tid * 8]);
        }
        __syncthreads();   // staging visible
        // ---- QK^T: 32x32 over D=256, two independent acc chains ----
        f32x16 sA, sB;
#pragma unroll
        for (int i = 0; i < 16; i++) { sA[i] = 0.f; sB[i] = 0.f; }
        const unsigned short* kb = &Ks[wc * 8192 + lhalf * 256 + l31 * 8];
#pragma unroll
        for (int s = 0; s < 16; s += 2) {
            bf16x8 b0 = ldg_frag(kb + s * 512);
            bf16x8 b1 = ldg_frag(kb + (s + 1) * 512);
            sA = __builtin_amdgcn_mfma_f32_32x32x16_bf16(qf[s],     b0, sA, 0, 0, 0);
            sB = __builtin_amdgcn_mfma_f32_32x32x16_bf16(qf[s + 1], b1, sB, 0, 0, 0);
        }
        float rk = rnk[kt * BK + wc * 32 + l31];
        // ---- P = exp(s*rq*rk - 1) (cosine: max = 1, no rescale) ----
#pragma unroll
        for (int i = 0; i < 16; i++) {
            float p = __expf((sA[i] + sB[i]) * rqv[i] * rk - 1.0f);
            unsigned short pb = f2bf(p);
            lpart[i] += bf2f(pb);
            int m = wr * 32 + (i & 3) + 8 * (i >> 2) + 4 * lhalf;
            Ps[m * 72 + wc * 32 + l31] = pb;
        }
        __syncthreads();   // P complete
        // ---- PV: rows wr*32, dims wc*128; A from Ps, B from Vs ----
#pragma unroll
        for (int ks = 0; ks < 4; ks++) {
            frag_cast ac;
            ac.u = *(const uint4*)&Ps[(wr * 32 + l31) * 72 + ks * 16 + lhalf * 8];
#pragma unroll
            for (int nt = 0; nt < 4; nt++) {
                bf16x8 bf = ldg_frag(&Vs[((wc * 4 + nt) * 8 + ks * 2 + lhalf) * 256 + l31 * 8]);
                xacc[nt] = __builtin_amdgcn_mfma_f32_32x32x16_bf16(ac.b, bf, xacc[nt], 0, 0, 0);
            }
        }
    }

    // ---- l: reduce over this wave's 32 key-cols; combine wc pair via LDS ----
#pragma unroll
    for (int i = 0; i < 16; i++) {
        float v = lpart[i];
#pragma unroll
        for (int off = 1; off < 32; off <<= 1) v += __shfl_xor(v, off, 64);
        if (l31 == 0) {
            int m = wr * 32 + (i & 3) + 8 * (i >> 2) + 4 * lhalf;
            ls[wc][m] = v;
        }
    }
    __syncthreads();
    if (tid < BM)
        lbuf[(size_t)mchunk * NROWS + r0 + tid] = ls[0][tid] + ls[1][tid];

    // ---- store X partial in row-frag order (bf16, no atomics) ----
    unsigned short* xout = Xp + (size_t)mchunk * XSPLIT +
                           (size_t)(rowblk * 2 + wr) * 8192;
#pragma unroll
    for (int nt = 0; nt < 4; nt++) {
        int dcol = wc * 128 + nt * 32 + l31;
        int cbase = (dcol >> 3) * 256 + (dcol & 7);
#pragma unroll
        for (int i = 0; i < 16; i++) {
            int m = (i & 3) + 8 * (i >> 2) + 4 * lhalf;
            xout[cbase + m * 8] = f2bf(xacc[nt][i]);
        }
    }
}

// ---------------- kernel 4: xnsw = (sum of 4 X splits) / (sum l) -------------
__global__ void reduce_kernel(const unsigned short* Xp, const float* lbuf,
                              unsigned short* xnsw) {
    int cg  = blockIdx.x * 256 + threadIdx.x;
    int row = (cg >> 10) * 32 + (cg & 31);
    float l = lbuf[row] + lbuf[NROWS + row] +
              lbuf[2 * NROWS + row] + lbuf[3 * NROWS + row];
    float rinv = 1.0f / l;
    const unsigned short* p = Xp + (size_t)cg * 8;
    frag_cast p0, p1, p2, p3, u;
    p0.u = *(const uint4*)p;
    p1.u = *(const uint4*)(p + (size_t)XSPLIT);
    p2.u = *(const uint4*)(p + 2 * (size_t)XSPLIT);
    p3.u = *(const uint4*)(p + 3 * (size_t)XSPLIT);
#pragma unroll
    for (int j = 0; j < 8; j++) {
        float f = bf2f(p0.h[j]) + bf2f(p1.h[j]) + bf2f(p2.h[j]) + bf2f(p3.h[j]);
        u.h[j] = f2bf(f * rinv);
    }
    *(uint4*)(xnsw + (size_t)cg * 8) = u.u;
}

// ---------------- kernel 5: h = relu([em1, xn] @ W^T + b), f32 out -----------
__global__ __launch_bounds__(256, 2)
void final_gemm(const unsigned short* e1sw, const unsigned short* xnsw,
                const unsigned short* wsw, const float* bias, float* out) {
    int tid = threadIdx.x, lane = tid & 63, w = tid >> 6;
    int l31 = lane & 31, lhalf = lane >> 5;
    int bid = blockIdx.x;
    int cb = bid & 3, rb = bid >> 2;
    int R0 = rb * 128 + 64 * (w & 1);
    int C0 = cb * 128 + 64 * (w >> 1);

    f32x16 acc[2][2];
#pragma unroll
    for (int a = 0; a < 2; a++)
#pragma unroll
        for (int b2 = 0; b2 < 2; b2++)
#pragma unroll
            for (int i = 0; i < 16; i++) acc[a][b2][i] = 0.f;

    for (int kk = 0; kk < 32; kk++) {
        bf16x8 afr[2], bfr[2];
#pragma unroll
        for (int mt = 0; mt < 2; mt++) {
            int gA = (R0 >> 5) + mt;
            const unsigned short* ap =
                (kk < 16) ? e1sw + (size_t)gA * 8192 + kk * 512
                          : xnsw + (size_t)gA * 8192 + (kk - 16) * 512;
            afr[mt] = ldg_frag(ap + lhalf * 256 + l31 * 8);
        }
#pragma unroll
        for (int nt = 0; nt < 2; nt++) {
            int gB = (C0 >> 5) + nt;
            bfr[nt] = ldg_frag(wsw + (size_t)gB * 16384 + kk * 512 + lhalf * 256 + l31 * 8);
        }
#pragma unroll
        for (int mt = 0; mt < 2; mt++)
#pragma unroll
            for (int nt = 0; nt < 2; nt++)
                acc[mt][nt] = __builtin_amdgcn_mfma_f32_32x32x16_bf16(
                    afr[mt], bfr[nt], acc[mt][nt], 0, 0, 0);
    }

#pragma unroll
    for (int nt = 0; nt < 2; nt++) {
        int col = C0 + nt * 32 + l31;
        float bb = bias[col];
#pragma unroll
        for (int mt = 0; mt < 2; mt++) {
#pragma unroll
            for (int i = 0; i < 16; i++) {
                int row = R0 + mt * 32 + (i & 3) + 8 * (i >> 2) + 4 * lhalf;
                float v = acc[mt][nt][i] + bb;
                v = v > 0.f ? v : 0.f;
                out[(size_t)row * ODIM + col] = v;
            }
        }
    }
}

// ---------------- launch ----------------
extern "C" void kernel_launch(void* const* d_in, const int* in_sizes, int n_in,
                              void* d_out, int out_size, void* d_ws, size_t ws_size,
                              hipStream_t stream) {
    const float* em1  = (const float*)d_in[0];
    const float* em2  = (const float*)d_in[1];
    const float* W    = (const float*)d_in[2];
    const float* bias = (const float*)d_in[3];
    float* out = (float*)d_out;

    char* ws = (char*)d_ws;
    unsigned short* e1sw = (unsigned short*)ws;                     // 4 MB
    unsigned short* ksw  = e1sw + (size_t)NROWS * DD;               // 4 MB
    unsigned short* vsw  = ksw  + (size_t)NROWS * DD;               // 4 MB
    unsigned short* wsw  = vsw  + (size_t)BATCH * DD * MK;          // 0.5 MB
    unsigned short* Xp   = wsw  + (size_t)ODIM * SDIM;              // 16 MB
    unsigned short* xnsw = Xp   + 4 * (size_t)XSPLIT;               // 4 MB
    float* lbuf = (float*)(xnsw + (size_t)NROWS * DD);              // 128 KB
    float* rn   = lbuf + 4 * (size_t)NROWS;                         // 64 KB

    rnorm_kernel<<<(2 * NROWS) / 4, 256, 0, stream>>>(em1, em2, rn);
    swizzle_kernel<<<(NCH_E1 + NCH_K + NCH_V + NCH_W + 255) / 256, 256, 0, stream>>>(
        em1, em2, W, e1sw, ksw, vsw, wsw);
    flash_kernel<<<(NROWS / BM) * MSPLIT, 256, 0, stream>>>(e1sw, ksw, vsw, rn, Xp, lbuf);
    reduce_kernel<<<NCH_E1 / 256, 256, 0, stream>>>(Xp, lbuf, xnsw);
    final_gemm<<<(NROWS / 128) * (ODIM / 128), 256, 0, stream>>>(
        e1sw, xnsw, wsw, bias, out);
}